// Round 9
// baseline (378.120 us; speedup 1.0000x reference)
//
#include <hip/hip_runtime.h>
#include <cstdint>
#include <cstddef>

typedef unsigned short u16;
typedef __bf16 bf16x8 __attribute__((ext_vector_type(8)));
typedef float f32x4 __attribute__((ext_vector_type(4)));

#define SLEN 2048
#define NHEADS 16
#define NGRP 4

__device__ inline float bf2f(u16 u) { return __uint_as_float(((unsigned)u) << 16); }
__device__ inline u16 f2bf(float f) {
    unsigned u = __float_as_uint(f);
    u += 0x7fffu + ((u >> 16) & 1u);
    return (u16)(u >> 16);
}

__device__ inline f32x4 mfma16(bf16x8 a, bf16x8 b, f32x4 c) {
    return __builtin_amdgcn_mfma_f32_16x16x32_bf16(a, b, c, 0, 0, 0);
}

__device__ inline void memfence_compiler() { __asm__ volatile("" ::: "memory"); }

// async global->LDS, 16B per lane; LDS dest = wave-uniform base + lane*16
__device__ inline void cp16(const u16* g, u16* l) {
    __builtin_amdgcn_global_load_lds(
        (__attribute__((address_space(1))) void*)(u16*)g,
        (__attribute__((address_space(3))) void*)l, 16, 0, 0);
}

// ---------------- device bodies for fused prep/mid kernels ----------------

__device__ inline void transpose_f32_body(u16 (*tile)[65], const float* __restrict__ in,
                                          u16* __restrict__ out, int R, int C, int bx, int by,
                                          int tid) {
    const long r0 = (long)by * 64, c0 = (long)bx * 64;
    for (int j = 0; j < 4; j++) {
        int c = j * 256 + tid;
        int lr = c >> 4, lc = (c & 15) * 4;
        float4 v = *(const float4*)&in[(r0 + lr) * (long)C + c0 + lc];
        tile[lr][lc + 0] = f2bf(v.x); tile[lr][lc + 1] = f2bf(v.y);
        tile[lr][lc + 2] = f2bf(v.z); tile[lr][lc + 3] = f2bf(v.w);
    }
    __syncthreads();
    for (int j = 0; j < 4; j++) {
        int c = j * 256 + tid;
        int orow = c >> 4, oc = (c & 15) * 4;
        ushort4 vv;
        vv.x = tile[oc + 0][orow]; vv.y = tile[oc + 1][orow];
        vv.z = tile[oc + 2][orow]; vv.w = tile[oc + 3][orow];
        *(ushort4*)&out[(c0 + orow) * (long)R + r0 + oc] = vv;
    }
}

__device__ inline void transpose_bf_body(u16 (*tile)[65], const u16* __restrict__ in, long inRS,
                                         u16* __restrict__ out, int R, int C, int bx, int by,
                                         int tid) {
    const long r0 = (long)by * 64, c0 = (long)bx * 64;
    for (int j = 0; j < 4; j++) {
        int c = j * 256 + tid;
        int lr = c >> 4, lc = (c & 15) * 4;
        ushort4 vv = *(const ushort4*)&in[(r0 + lr) * inRS + c0 + lc];
        tile[lr][lc + 0] = vv.x; tile[lr][lc + 1] = vv.y;
        tile[lr][lc + 2] = vv.z; tile[lr][lc + 3] = vv.w;
    }
    __syncthreads();
    for (int j = 0; j < 4; j++) {
        int c = j * 256 + tid;
        int orow = c >> 4, oc = (c & 15) * 4;
        ushort4 vv;
        vv.x = tile[oc + 0][orow]; vv.y = tile[oc + 1][orow];
        vv.z = tile[oc + 2][orow]; vv.w = tile[oc + 3][orow];
        *(ushort4*)&out[(c0 + orow) * (long)R + r0 + oc] = vv;
    }
}

__device__ inline void normrope_body(u16* __restrict__ buf, long rowstride, int heads,
                                     const u16* __restrict__ w,
                                     const float* __restrict__ cosf, const float* __restrict__ sinf,
                                     float scale, int row, int lane) {
    u16* p = buf + (long)(row / heads) * rowstride + (row % heads) * 128;
    float x1 = bf2f(p[lane]);
    float x2 = bf2f(p[lane + 64]);
    float ss = x1 * x1 + x2 * x2;
    for (int off = 1; off < 64; off <<= 1) ss += __shfl_xor(ss, off);
    float inv = rsqrtf(ss * (1.f / 128.f) + 1e-6f);
    int s = (row / heads) % SLEN;
    float c1 = cosf[s * 128 + lane], c2 = cosf[s * 128 + 64 + lane];
    float s1 = sinf[s * 128 + lane], s2 = sinf[s * 128 + 64 + lane];
    float w1 = bf2f(w[lane]), w2 = bf2f(w[lane + 64]);
    float y1 = x1 * inv * w1, y2 = x2 * inv * w2;
    p[lane]      = f2bf((y1 * c1 - y2 * s1) * scale);
    p[lane + 64] = f2bf((y2 * c2 + y1 * s2) * scale);
}

// ---------------- PREP: convert x + convert qw/kw + Wq/Wk/Wv transposes (1 launch) ----------
__global__ __launch_bounds__(256) void prep_k(const float* __restrict__ x, u16* __restrict__ xbf,
                                              const float* __restrict__ qw, const float* __restrict__ kw,
                                              u16* qwb, u16* kwb,
                                              const float* __restrict__ Wq, const float* __restrict__ Wk,
                                              const float* __restrict__ Wv, u16* __restrict__ wqkvT) {
    __shared__ u16 tile[64][65];
    const int bid = blockIdx.x, tid = threadIdx.x;
    if (bid < 8192) {
        long i = ((long)bid * 256 + tid) * 4;
        float4 v = *(const float4*)(x + i);
        ushort4 o;
        o.x = f2bf(v.x); o.y = f2bf(v.y); o.z = f2bf(v.z); o.w = f2bf(v.w);
        *(ushort4*)(xbf + i) = o;
    } else if (bid == 8192) {
        if (tid < 128) qwb[tid] = f2bf(qw[tid]);
        else kwb[tid - 128] = f2bf(kw[tid - 128]);
    } else if (bid < 9217) {
        int rem = bid - 8193;
        transpose_f32_body(tile, Wq, wqkvT, 2048, 2048, rem & 31, rem >> 5, tid);
    } else if (bid < 9473) {
        int rem = bid - 9217;
        transpose_f32_body(tile, Wk, wqkvT + 2048L * 2048, 2048, 512, rem & 7, rem >> 3, tid);
    } else {
        int rem = bid - 9473;
        transpose_f32_body(tile, Wv, wqkvT + 2560L * 2048, 2048, 512, rem & 7, rem >> 3, tid);
    }
}

// ---------------- MID: vT transpose + normrope(q) + normrope(k) + Wo^T (1 launch) ----------
__global__ __launch_bounds__(256) void mid_k(u16* __restrict__ qkvb, u16* __restrict__ vTb,
                                             const u16* __restrict__ qwb, const u16* __restrict__ kwb,
                                             const float* __restrict__ cosf, const float* __restrict__ sinf,
                                             const float* __restrict__ Wo, u16* __restrict__ woT) {
    __shared__ u16 tile[64][65];
    const int bid = blockIdx.x, tid = threadIdx.x;
    if (bid < 512) {
        transpose_bf_body(tile, qkvb + 2560, 3072L, vTb, 4096, 512, bid & 7, bid >> 3, tid);
    } else if (bid < 16896) {
        int row = (bid - 512) * 4 + (tid >> 6);
        normrope_body(qkvb, 3072L, NHEADS, qwb, cosf, sinf, 0.08838834764831845f, row, tid & 63);
    } else if (bid < 20992) {
        int row = (bid - 16896) * 4 + (tid >> 6);
        normrope_body(qkvb + 2048, 3072L, NGRP, kwb, cosf, sinf, 1.0f, row, tid & 63);
    } else {
        int rem = bid - 20992;
        transpose_f32_body(tile, Wo, woT, 2048, 2048, rem & 31, rem >> 5, tid);
    }
}

// ---------------- GEMM: 8-phase + XCD swizzle + counted lgkmcnt read-ahead ----------------
template <typename OutT, int NI>
__global__ __launch_bounds__(512, 2) void gemm8p(const u16* __restrict__ A, const u16* __restrict__ Bt,
                                                 OutT* __restrict__ C, int N, int K) {
    extern __shared__ u16 smem[];
    constexpr int AUNIT = 8192;            // 256 x 32 u16
    constexpr int BUNIT = NI * 2048;       // BN x 32 u16
    const int tid = threadIdx.x;
    const int lane = tid & 63, wave = tid >> 6;
    const int l15 = lane & 15, quad = lane >> 4;
    const int wm = (wave >> 2) * 128, wn = (wave & 3) * (NI * 16);

    const int nbx = gridDim.x;
    const int nwg = nbx * gridDim.y;
    const int d = blockIdx.y * nbx + blockIdx.x;
    const int s = (d & 7) * (nwg >> 3) + (d >> 3);
    const long m0 = (long)(s / nbx) * 256, n0 = (long)(s % nbx) * (NI * 64);

    f32x4 acc[8][NI];
    #pragma unroll
    for (int i = 0; i < 8; i++)
        #pragma unroll
        for (int j = 0; j < NI; j++) acc[i][j] = {0.f, 0.f, 0.f, 0.f};

    const u16* aBase = A + m0 * (long)K;
    const u16* bBase = Bt + n0 * (long)K;

    auto stageA = [&](int kt, int c, int k) {
        u16* dst = smem + (c * 2 + k) * AUNIT + wave * 512;
        #pragma unroll
        for (int i = 0; i < 2; i++) {
            int cd = i * 512 + wave * 64 + lane;
            int r = cd >> 2;
            int js = (cd & 3) ^ ((r >> 1) & 3);
            cp16(aBase + (long)r * K + kt + k * 32 + js * 8, dst + i * 4096);
        }
    };
    auto stageB = [&](int kt, int c, int k) {
        u16* dst = smem + 4 * AUNIT + (c * 2 + k) * BUNIT + wave * 512;
        #pragma unroll
        for (int i = 0; i < NI / 2; i++) {
            int cd = i * 512 + wave * 64 + lane;
            int r = cd >> 2;
            int js = (cd & 3) ^ ((r >> 1) & 3);
            cp16(bBase + (long)r * K + kt + k * 32 + js * 8, dst + i * 4096);
        }
    };

    stageA(0, 0, 0); stageB(0, 0, 0); stageA(0, 0, 1); stageB(0, 0, 1);

    const int nkt = K >> 6;

    for (int t = 0; t < nkt; ++t) {
        const int c = t & 1;
        const int kt1 = (t + 1) << 6;
        const bool more = (t + 1) < nkt;
        #pragma unroll
        for (int k = 0; k < 2; ++k) {
            if (k == 0 || more) {
                if constexpr (NI == 4) asm volatile("s_waitcnt vmcnt(4)" ::: "memory");
                else                   asm volatile("s_waitcnt vmcnt(3)" ::: "memory");
            } else {
                asm volatile("s_waitcnt vmcnt(0)" ::: "memory");
            }
            __builtin_amdgcn_s_barrier();

            const u16* au = smem + (c * 2 + k) * AUNIT;
            const u16* bu = smem + 4 * AUNIT + (c * 2 + k) * BUNIT;

            bf16x8 bfr[NI], af0[4], af1[4];
            #pragma unroll
            for (int ni = 0; ni < NI; ni++) {
                const int r = wn + ni * 16 + l15;
                bfr[ni] = *(const bf16x8*)&bu[r * 32 + (quad ^ ((r >> 1) & 3)) * 8];
            }
            #pragma unroll
            for (int mi = 0; mi < 4; mi++) {
                const int r = wm + mi * 16 + l15;
                af0[mi] = *(const bf16x8*)&au[r * 32 + (quad ^ ((r >> 1) & 3)) * 8];
            }
            #pragma unroll
            for (int mi = 0; mi < 4; mi++) {
                const int r = wm + 64 + mi * 16 + l15;
                af1[mi] = *(const bf16x8*)&au[r * 32 + (quad ^ ((r >> 1) & 3)) * 8];
            }
            if (more) stageA(kt1, c ^ 1, k);
            asm volatile("s_waitcnt lgkmcnt(4)" ::: "memory");
            __builtin_amdgcn_sched_barrier(0);
            __builtin_amdgcn_s_setprio(1);
            #pragma unroll
            for (int mi = 0; mi < 4; mi++)
                #pragma unroll
                for (int ni = 0; ni < NI; ni++)
                    acc[mi][ni] = mfma16(af0[mi], bfr[ni], acc[mi][ni]);
            __builtin_amdgcn_s_setprio(0);
            __builtin_amdgcn_s_barrier();

            if (more) stageB(kt1, c ^ 1, k);
            asm volatile("s_waitcnt lgkmcnt(0)" ::: "memory");
            __builtin_amdgcn_sched_barrier(0);
            __builtin_amdgcn_s_setprio(1);
            #pragma unroll
            for (int mi = 0; mi < 4; mi++)
                #pragma unroll
                for (int ni = 0; ni < NI; ni++)
                    acc[4 + mi][ni] = mfma16(af1[mi], bfr[ni], acc[4 + mi][ni]);
            __builtin_amdgcn_s_setprio(0);
            __builtin_amdgcn_s_barrier();
        }
    }

    #pragma unroll
    for (int mi = 0; mi < 8; mi++)
        #pragma unroll
        for (int r = 0; r < 4; r++) {
            long row = m0 + wm + mi * 16 + quad * 4 + r;
            OutT* crow = C + row * (long)N + n0 + wn + l15;
            #pragma unroll
            for (int ni = 0; ni < NI; ni++) {
                float v = acc[mi][ni][r];
                if constexpr (sizeof(OutT) == 2) crow[ni * 16] = f2bf(v);
                else crow[ni * 16] = v;
            }
        }
}

// ---------------- causal flash attention v9: LDS K + direct-L2 V ----------------
// Diagnosis (r8): attn is LDS-pipe-throughput-bound: ~44 LDS instrs/wave/tile x 8 resident
// waves oversubscribes the per-CU LDS pipe (+3.78M conflict cyc). v9 moves V fragments OUT
// of LDS: direct global b128 reads from vT (L2-resident, 1MB/XCD working set; addressing
// verified in v3), issued BEFORE the staging barrier so L2 latency hides under barrier +
// K-frag reads + QK MFMAs. LDS instrs/wave/tile 44 -> 28; staging cp16 8 -> 4/thread;
// LDS 50.5 -> 34 KB. Schedule = v5 (complementary pairing, longest first). Body = v5.
__global__ __launch_bounds__(256, 2) void attn(const u16* __restrict__ qkv, const u16* __restrict__ vT,
                                               u16* __restrict__ ctx) {
    __shared__ u16 KB[64 * 128];       // K tile: row t (64) x col d (128), swizzled
    __shared__ u16 Ps[4][2][16][72];   // [wave][m][qrow16][t+pad]
    __shared__ float Al[4][2][16];     // alpha axis-swap
    const int tid = threadIdx.x;
    const int lane = tid & 63, wave = tid >> 6;
    const int l15 = lane & 15, quad = lane >> 4;
    const int bg = blockIdx.x & 7, b = bg >> 2, g = bg & 3;
    const int rest = blockIdx.x >> 3;
    const int h = g * 4 + (rest & 3);
    const int idx = rest >> 2;
    const int qt = (idx < 8) ? (15 - idx) : (idx - 8);   // complementary pairing
    const int wr = qt * 128 + wave * 32;

    union { bf16x8 v; u16 s[8]; } uo;
    for (int j = 0; j < 8; j++) uo.s[j] = 0x3F80;
    const bf16x8 ones = uo.v;

    bf16x8 qa[2][4];
    for (int m = 0; m < 2; m++) {
        const u16* qp = qkv + (long)(b * SLEN + wr + m * 16 + l15) * 3072 + h * 128 + quad * 8;
        for (int kc = 0; kc < 4; kc++) qa[m][kc] = *(const bf16x8*)(qp + kc * 32);
    }
    float m_i[2] = {-__builtin_inff(), -__builtin_inff()};
    f32x4 l_acc[2];
    f32x4 o[2][8];
    for (int m = 0; m < 2; m++) l_acc[m] = {0.f, 0.f, 0.f, 0.f};
    for (int m = 0; m < 2; m++)
        for (int nf = 0; nf < 8; nf++) o[m][nf] = {0.f, 0.f, 0.f, 0.f};

    const u16* kqb = qkv + (long)b * SLEN * 3072 + 2048 + g * 128;
    const u16* vgb = vT + (long)g * 128 * 4096 + (long)b * SLEN;
    const int xk = (l15 & 7) << 4;
    const int nt = 2 * qt + 2;

    for (int t = 0; t < nt; ++t) {
        const int t0 = t * 64;
        const bool live = (t0 <= wr + 31);
        // ---- stage K into LDS (4 cp16/thread); linear dest, pre-swizzled source ----
        #pragma unroll
        for (int i = 0; i < 4; ++i) {
            const int j = wave * 4 + i;
            const int row = j * 4 + (lane >> 4);
            const int cs = lane & 15;
            cp16(kqb + (long)(t0 + row) * 3072 + ((cs ^ (row & 7)) * 8), &KB[j * 512]);
        }
        // ---- V fragments direct from global/L2, issued before the barrier ----
        bf16x8 vf0[8], vf1[8];
        if (live) {
            #pragma unroll
            for (int nf = 0; nf < 8; nf++)
                vf0[nf] = *(const bf16x8*)(vgb + (long)(nf * 16 + l15) * 4096 + t0 + quad * 8);
            #pragma unroll
            for (int nf = 0; nf < 8; nf++)
                vf1[nf] = *(const bf16x8*)(vgb + (long)(nf * 16 + l15) * 4096 + t0 + 32 + quad * 8);
        }
        __syncthreads();   // K staging visible

        if (live) {
            bf16x8 kf[4][4];
            #pragma unroll
            for (int nf = 0; nf < 4; nf++)
                #pragma unroll
                for (int kc = 0; kc < 4; kc++)
                    kf[nf][kc] = *(const bf16x8*)((const char*)KB +
                                  (nf * 16 + l15) * 256 + ((quad * 16 + kc * 64) ^ xk));

            f32x4 sc[2][4];
            for (int m = 0; m < 2; m++)
                for (int nf = 0; nf < 4; nf++) sc[m][nf] = {0.f, 0.f, 0.f, 0.f};
            #pragma unroll
            for (int kc = 0; kc < 4; kc++)
                #pragma unroll
                for (int nf = 0; nf < 4; nf++) {
                    sc[0][nf] = mfma16(kf[nf][kc], qa[0][kc], sc[0][nf]);
                    sc[1][nf] = mfma16(kf[nf][kc], qa[1][kc], sc[1][nf]);
                }
            if (t0 + 63 > wr) {
                #pragma unroll
                for (int m = 0; m < 2; m++) {
                    int qrow = wr + m * 16 + l15;
                    #pragma unroll
                    for (int nf = 0; nf < 4; nf++)
                        #pragma unroll
                        for (int r = 0; r < 4; r++)
                            if (t0 + nf * 16 + quad * 4 + r > qrow) sc[m][nf][r] = -__builtin_inff();
                }
            }
            float alpha[2];
            #pragma unroll
            for (int m = 0; m < 2; m++) {
                float mx = sc[m][0][0];
                #pragma unroll
                for (int nf = 0; nf < 4; nf++)
                    #pragma unroll
                    for (int r = 0; r < 4; r++) mx = fmaxf(mx, sc[m][nf][r]);
                mx = fmaxf(mx, __shfl_xor(mx, 16));
                mx = fmaxf(mx, __shfl_xor(mx, 32));
                float mn = fmaxf(m_i[m], mx);
                alpha[m] = __expf(m_i[m] - mn);
                m_i[m] = mn;
                Al[wave][m][l15] = alpha[m];
            }
            #pragma unroll
            for (int m = 0; m < 2; m++)
                #pragma unroll
                for (int nf = 0; nf < 4; nf++) {
                    ushort4 pk;
                    pk.x = f2bf(__expf(sc[m][nf][0] - m_i[m]));
                    pk.y = f2bf(__expf(sc[m][nf][1] - m_i[m]));
                    pk.z = f2bf(__expf(sc[m][nf][2] - m_i[m]));
                    pk.w = f2bf(__expf(sc[m][nf][3] - m_i[m]));
                    *(ushort4*)&Ps[wave][m][l15][nf * 16 + quad * 4] = pk;
                }
            memfence_compiler();
            f32x4 al[2];
            al[0] = *(const f32x4*)&Al[wave][0][quad * 4];
            al[1] = *(const f32x4*)&Al[wave][1][quad * 4];
            #pragma unroll
            for (int m = 0; m < 2; m++) {
                #pragma unroll
                for (int nf = 0; nf < 8; nf++)
                    #pragma unroll
                    for (int r = 0; r < 4; r++) o[m][nf][r] *= al[m][r];
                #pragma unroll
                for (int r = 0; r < 4; r++) l_acc[m][r] *= al[m][r];
            }
            // PV, half 0 (V already in registers)
            {
                bf16x8 pa0 = *(const bf16x8*)&Ps[wave][0][l15][quad * 8];
                bf16x8 pa1 = *(const bf16x8*)&Ps[wave][1][l15][quad * 8];
                #pragma unroll
                for (int nf = 0; nf < 8; nf++) {
                    o[0][nf] = mfma16(pa0, vf0[nf], o[0][nf]);
                    o[1][nf] = mfma16(pa1, vf0[nf], o[1][nf]);
                }
                l_acc[0] = mfma16(pa0, ones, l_acc[0]);
                l_acc[1] = mfma16(pa1, ones, l_acc[1]);
            }
            // PV, half 1
            {
                bf16x8 pa0 = *(const bf16x8*)&Ps[wave][0][l15][32 + quad * 8];
                bf16x8 pa1 = *(const bf16x8*)&Ps[wave][1][l15][32 + quad * 8];
                #pragma unroll
                for (int nf = 0; nf < 8; nf++) {
                    o[0][nf] = mfma16(pa0, vf1[nf], o[0][nf]);
                    o[1][nf] = mfma16(pa1, vf1[nf], o[1][nf]);
                }
                l_acc[0] = mfma16(pa0, ones, l_acc[0]);
                l_acc[1] = mfma16(pa1, ones, l_acc[1]);
            }
            memfence_compiler();
        }
        __syncthreads();   // all KB reads done before next tile's overwrite
    }

    #pragma unroll
    for (int m = 0; m < 2; m++)
        #pragma unroll
        for (int r = 0; r < 4; r++) {
            float inv = 1.f / l_acc[m][r];
            int srow = wr + m * 16 + quad * 4 + r;
            u16* cp = ctx + (long)(b * SLEN + srow) * 2048 + h * 128 + l15;
            #pragma unroll
            for (int nf = 0; nf < 8; nf++) cp[nf * 16] = f2bf(o[m][nf][r] * inv);
        }
}

extern "C" void kernel_launch(void* const* d_in, const int* in_sizes, int n_in,
                              void* d_out, int out_size, void* d_ws, size_t ws_size,
                              hipStream_t stream) {
    const float* x    = (const float*)d_in[0];
    const float* cosi = (const float*)d_in[2];
    const float* sini = (const float*)d_in[3];
    const float* Wq   = (const float*)d_in[4];
    const float* Wk   = (const float*)d_in[5];
    const float* Wv   = (const float*)d_in[6];
    const float* Wo   = (const float*)d_in[7];
    const float* qw   = (const float*)d_in[8];
    const float* kw   = (const float*)d_in[9];
    float* out = (float*)d_out;
    char* ws = (char*)d_ws;

    const size_t MB = 1 << 20;
    u16* qkvb  = (u16*)(ws);             // 4096x3072 bf16 = 24 MB  [0,24)
    u16* vTb   = (u16*)(ws + 24 * MB);   // 512x4096        = 4 MB  [24,28)
    u16* xbf   = (u16*)(ws + 28 * MB);   // 4096x2048       = 16 MB [28,44)
    u16* ctx   = (u16*)(ws + 28 * MB);   // reuses xbf region
    u16* wqkvT = (u16*)(ws + 44 * MB);   // 3072x2048       = 12 MB [44,56)
    u16* woT   = (u16*)(ws + 44 * MB);   // reuses wqkvT region
    u16* qwb   = (u16*)(ws + 56 * MB);
    u16* kwb   = (u16*)(ws + 56 * MB + 256);

    // 1) prep: convert x, convert qw/kw, transpose Wq/Wk/Wv into fused wqkvT
    prep_k<<<9729, 256, 0, stream>>>(x, xbf, qw, kw, qwb, kwb, Wq, Wk, Wv, wqkvT);

    // 2) QKV GEMM (8-phase + XCD swizzle): (4096x2048) x (3072x2048)^T -> 4096x3072 bf16
    gemm8p<u16, 4><<<dim3(12, 16), 512, 131072, stream>>>(xbf, wqkvT, qkvb, 3072, 2048);

    // 3) mid: vT transpose, normrope q, normrope k, Wo^T
    mid_k<<<22016, 256, 0, stream>>>(qkvb, vTb, qwb, kwb, cosi, sini, Wo, woT);

    // 4) attention (LDS K + direct-L2 V)
    attn<<<dim3(512, 1, 1), 256, 0, stream>>>(qkvb, vTb, ctx);

    // 5) out GEMM (8-phase + XCD swizzle, BN=128 -> 256 blocks, full CU util)
    gemm8p<float, 2><<<dim3(16, 16), 512, 98304, stream>>>(ctx, woT, out, 2048, 2048);
}

// Round 10
// 313.813 us; speedup vs baseline: 1.2049x; 1.2049x over previous
//
#include <hip/hip_runtime.h>
#include <cstdint>
#include <cstddef>

typedef unsigned short u16;
typedef __bf16 bf16x8 __attribute__((ext_vector_type(8)));
typedef float f32x4 __attribute__((ext_vector_type(4)));

#define SLEN 2048
#define NHEADS 16
#define NGRP 4

__device__ inline float bf2f(u16 u) { return __uint_as_float(((unsigned)u) << 16); }
__device__ inline u16 f2bf(float f) {
    unsigned u = __float_as_uint(f);
    u += 0x7fffu + ((u >> 16) & 1u);
    return (u16)(u >> 16);
}

__device__ inline f32x4 mfma16(bf16x8 a, bf16x8 b, f32x4 c) {
    return __builtin_amdgcn_mfma_f32_16x16x32_bf16(a, b, c, 0, 0, 0);
}

__device__ inline void memfence_compiler() { __asm__ volatile("" ::: "memory"); }

// async global->LDS, 16B per lane; LDS dest = wave-uniform base + lane*16
__device__ inline void cp16(const u16* g, u16* l) {
    __builtin_amdgcn_global_load_lds(
        (__attribute__((address_space(1))) void*)(u16*)g,
        (__attribute__((address_space(3))) void*)l, 16, 0, 0);
}

// ---------------- device bodies for fused prep/mid kernels ----------------

__device__ inline void transpose_f32_body(u16 (*tile)[65], const float* __restrict__ in,
                                          u16* __restrict__ out, int R, int C, int bx, int by,
                                          int tid) {
    const long r0 = (long)by * 64, c0 = (long)bx * 64;
    for (int j = 0; j < 4; j++) {
        int c = j * 256 + tid;
        int lr = c >> 4, lc = (c & 15) * 4;
        float4 v = *(const float4*)&in[(r0 + lr) * (long)C + c0 + lc];
        tile[lr][lc + 0] = f2bf(v.x); tile[lr][lc + 1] = f2bf(v.y);
        tile[lr][lc + 2] = f2bf(v.z); tile[lr][lc + 3] = f2bf(v.w);
    }
    __syncthreads();
    for (int j = 0; j < 4; j++) {
        int c = j * 256 + tid;
        int orow = c >> 4, oc = (c & 15) * 4;
        ushort4 vv;
        vv.x = tile[oc + 0][orow]; vv.y = tile[oc + 1][orow];
        vv.z = tile[oc + 2][orow]; vv.w = tile[oc + 3][orow];
        *(ushort4*)&out[(c0 + orow) * (long)R + r0 + oc] = vv;
    }
}

__device__ inline void transpose_bf_body(u16 (*tile)[65], const u16* __restrict__ in, long inRS,
                                         u16* __restrict__ out, int R, int C, int bx, int by,
                                         int tid) {
    const long r0 = (long)by * 64, c0 = (long)bx * 64;
    for (int j = 0; j < 4; j++) {
        int c = j * 256 + tid;
        int lr = c >> 4, lc = (c & 15) * 4;
        ushort4 vv = *(const ushort4*)&in[(r0 + lr) * inRS + c0 + lc];
        tile[lr][lc + 0] = vv.x; tile[lr][lc + 1] = vv.y;
        tile[lr][lc + 2] = vv.z; tile[lr][lc + 3] = vv.w;
    }
    __syncthreads();
    for (int j = 0; j < 4; j++) {
        int c = j * 256 + tid;
        int orow = c >> 4, oc = (c & 15) * 4;
        ushort4 vv;
        vv.x = tile[oc + 0][orow]; vv.y = tile[oc + 1][orow];
        vv.z = tile[oc + 2][orow]; vv.w = tile[oc + 3][orow];
        *(ushort4*)&out[(c0 + orow) * (long)R + r0 + oc] = vv;
    }
}

// RMSNorm + RoPE, vectorized (G13): one wave per 128-elem head-row; lane l owns elems
// (2l, 2l+1) via ushort2 load (wave = 256B in 1 instr). RoPE partner (d, d+64) is 32
// lanes away -> shfl_xor(normed y, 32). Arithmetic per output element identical to the
// scalar version (same products, same order) -> bit-identical results.
__device__ inline void normrope_body(u16* __restrict__ buf, long rowstride, int heads,
                                     const u16* __restrict__ w,
                                     const float* __restrict__ cosf, const float* __restrict__ sinf,
                                     float scale, int row, int lane) {
    u16* p = buf + (long)(row / heads) * rowstride + (row % heads) * 128;
    ushort2 pv = *(const ushort2*)(p + 2 * lane);
    float e0 = bf2f(pv.x), e1 = bf2f(pv.y);
    float ss = e0 * e0 + e1 * e1;
    for (int off = 1; off < 64; off <<= 1) ss += __shfl_xor(ss, off);
    float inv = rsqrtf(ss * (1.f / 128.f) + 1e-6f);
    int s = (row / heads) % SLEN;
    float2 cv = *(const float2*)(cosf + s * 128 + 2 * lane);
    float2 sv = *(const float2*)(sinf + s * 128 + 2 * lane);
    ushort2 wv = *(const ushort2*)(w + 2 * lane);
    float y0 = e0 * inv * bf2f(wv.x);
    float y1 = e1 * inv * bf2f(wv.y);
    float q0 = __shfl_xor(y0, 32);   // partner's normed value at d^64
    float q1 = __shfl_xor(y1, 32);
    float o0, o1;
    if (lane < 32) { o0 = (y0 * cv.x - q0 * sv.x) * scale; o1 = (y1 * cv.y - q1 * sv.y) * scale; }
    else           { o0 = (y0 * cv.x + q0 * sv.x) * scale; o1 = (y1 * cv.y + q1 * sv.y) * scale; }
    ushort2 ov; ov.x = f2bf(o0); ov.y = f2bf(o1);
    *(ushort2*)(p + 2 * lane) = ov;
}

// ---------------- PREP: convert x (8 elem/thread) + qw/kw + Wq/Wk/Wv transposes ----------
// blocks [0,4096): x fp32->bf16 | 4096: qw/kw | (4096,5121): Wq^T | [5121,5377): Wk^T
// [5377,5633): Wv^T
__global__ __launch_bounds__(256) void prep_k(const float* __restrict__ x, u16* __restrict__ xbf,
                                              const float* __restrict__ qw, const float* __restrict__ kw,
                                              u16* qwb, u16* kwb,
                                              const float* __restrict__ Wq, const float* __restrict__ Wk,
                                              const float* __restrict__ Wv, u16* __restrict__ wqkvT) {
    __shared__ u16 tile[64][65];
    const int bid = blockIdx.x, tid = threadIdx.x;
    if (bid < 4096) {
        long i = ((long)bid * 256 + tid) * 8;
        float4 a = *(const float4*)(x + i);
        float4 b4 = *(const float4*)(x + i + 4);
        ushort4 o1, o2;
        o1.x = f2bf(a.x); o1.y = f2bf(a.y); o1.z = f2bf(a.z); o1.w = f2bf(a.w);
        o2.x = f2bf(b4.x); o2.y = f2bf(b4.y); o2.z = f2bf(b4.z); o2.w = f2bf(b4.w);
        *(ushort4*)(xbf + i) = o1;
        *(ushort4*)(xbf + i + 4) = o2;
    } else if (bid == 4096) {
        if (tid < 128) qwb[tid] = f2bf(qw[tid]);
        else kwb[tid - 128] = f2bf(kw[tid - 128]);
    } else if (bid < 5121) {
        int rem = bid - 4097;
        transpose_f32_body(tile, Wq, wqkvT, 2048, 2048, rem & 31, rem >> 5, tid);
    } else if (bid < 5377) {
        int rem = bid - 5121;
        transpose_f32_body(tile, Wk, wqkvT + 2048L * 2048, 2048, 512, rem & 7, rem >> 3, tid);
    } else {
        int rem = bid - 5377;
        transpose_f32_body(tile, Wv, wqkvT + 2560L * 2048, 2048, 512, rem & 7, rem >> 3, tid);
    }
}

// ---------------- MID: vT transpose + normrope(q) + normrope(k) + Wo^T (1 launch) ----------
__global__ __launch_bounds__(256) void mid_k(u16* __restrict__ qkvb, u16* __restrict__ vTb,
                                             const u16* __restrict__ qwb, const u16* __restrict__ kwb,
                                             const float* __restrict__ cosf, const float* __restrict__ sinf,
                                             const float* __restrict__ Wo, u16* __restrict__ woT) {
    __shared__ u16 tile[64][65];
    const int bid = blockIdx.x, tid = threadIdx.x;
    if (bid < 512) {
        transpose_bf_body(tile, qkvb + 2560, 3072L, vTb, 4096, 512, bid & 7, bid >> 3, tid);
    } else if (bid < 16896) {
        int row = (bid - 512) * 4 + (tid >> 6);
        normrope_body(qkvb, 3072L, NHEADS, qwb, cosf, sinf, 0.08838834764831845f, row, tid & 63);
    } else if (bid < 20992) {
        int row = (bid - 16896) * 4 + (tid >> 6);
        normrope_body(qkvb + 2048, 3072L, NGRP, kwb, cosf, sinf, 1.0f, row, tid & 63);
    } else {
        int rem = bid - 20992;
        transpose_f32_body(tile, Wo, woT, 2048, 2048, rem & 31, rem >> 5, tid);
    }
}

// ---------------- GEMM: 8-phase + XCD swizzle + counted lgkmcnt read-ahead ----------------
template <typename OutT, int NI>
__global__ __launch_bounds__(512, 2) void gemm8p(const u16* __restrict__ A, const u16* __restrict__ Bt,
                                                 OutT* __restrict__ C, int N, int K) {
    extern __shared__ u16 smem[];
    constexpr int AUNIT = 8192;            // 256 x 32 u16
    constexpr int BUNIT = NI * 2048;       // BN x 32 u16
    const int tid = threadIdx.x;
    const int lane = tid & 63, wave = tid >> 6;
    const int l15 = lane & 15, quad = lane >> 4;
    const int wm = (wave >> 2) * 128, wn = (wave & 3) * (NI * 16);

    const int nbx = gridDim.x;
    const int nwg = nbx * gridDim.y;
    const int d = blockIdx.y * nbx + blockIdx.x;
    const int s = (d & 7) * (nwg >> 3) + (d >> 3);
    const long m0 = (long)(s / nbx) * 256, n0 = (long)(s % nbx) * (NI * 64);

    f32x4 acc[8][NI];
    #pragma unroll
    for (int i = 0; i < 8; i++)
        #pragma unroll
        for (int j = 0; j < NI; j++) acc[i][j] = {0.f, 0.f, 0.f, 0.f};

    const u16* aBase = A + m0 * (long)K;
    const u16* bBase = Bt + n0 * (long)K;

    auto stageA = [&](int kt, int c, int k) {
        u16* dst = smem + (c * 2 + k) * AUNIT + wave * 512;
        #pragma unroll
        for (int i = 0; i < 2; i++) {
            int cd = i * 512 + wave * 64 + lane;
            int r = cd >> 2;
            int js = (cd & 3) ^ ((r >> 1) & 3);
            cp16(aBase + (long)r * K + kt + k * 32 + js * 8, dst + i * 4096);
        }
    };
    auto stageB = [&](int kt, int c, int k) {
        u16* dst = smem + 4 * AUNIT + (c * 2 + k) * BUNIT + wave * 512;
        #pragma unroll
        for (int i = 0; i < NI / 2; i++) {
            int cd = i * 512 + wave * 64 + lane;
            int r = cd >> 2;
            int js = (cd & 3) ^ ((r >> 1) & 3);
            cp16(bBase + (long)r * K + kt + k * 32 + js * 8, dst + i * 4096);
        }
    };

    stageA(0, 0, 0); stageB(0, 0, 0); stageA(0, 0, 1); stageB(0, 0, 1);

    const int nkt = K >> 6;

    for (int t = 0; t < nkt; ++t) {
        const int c = t & 1;
        const int kt1 = (t + 1) << 6;
        const bool more = (t + 1) < nkt;
        #pragma unroll
        for (int k = 0; k < 2; ++k) {
            if (k == 0 || more) {
                if constexpr (NI == 4) asm volatile("s_waitcnt vmcnt(4)" ::: "memory");
                else                   asm volatile("s_waitcnt vmcnt(3)" ::: "memory");
            } else {
                asm volatile("s_waitcnt vmcnt(0)" ::: "memory");
            }
            __builtin_amdgcn_s_barrier();

            const u16* au = smem + (c * 2 + k) * AUNIT;
            const u16* bu = smem + 4 * AUNIT + (c * 2 + k) * BUNIT;

            bf16x8 bfr[NI], af0[4], af1[4];
            #pragma unroll
            for (int ni = 0; ni < NI; ni++) {
                const int r = wn + ni * 16 + l15;
                bfr[ni] = *(const bf16x8*)&bu[r * 32 + (quad ^ ((r >> 1) & 3)) * 8];
            }
            #pragma unroll
            for (int mi = 0; mi < 4; mi++) {
                const int r = wm + mi * 16 + l15;
                af0[mi] = *(const bf16x8*)&au[r * 32 + (quad ^ ((r >> 1) & 3)) * 8];
            }
            #pragma unroll
            for (int mi = 0; mi < 4; mi++) {
                const int r = wm + 64 + mi * 16 + l15;
                af1[mi] = *(const bf16x8*)&au[r * 32 + (quad ^ ((r >> 1) & 3)) * 8];
            }
            if (more) stageA(kt1, c ^ 1, k);
            asm volatile("s_waitcnt lgkmcnt(4)" ::: "memory");
            __builtin_amdgcn_sched_barrier(0);
            __builtin_amdgcn_s_setprio(1);
            #pragma unroll
            for (int mi = 0; mi < 4; mi++)
                #pragma unroll
                for (int ni = 0; ni < NI; ni++)
                    acc[mi][ni] = mfma16(af0[mi], bfr[ni], acc[mi][ni]);
            __builtin_amdgcn_s_setprio(0);
            __builtin_amdgcn_s_barrier();

            if (more) stageB(kt1, c ^ 1, k);
            asm volatile("s_waitcnt lgkmcnt(0)" ::: "memory");
            __builtin_amdgcn_sched_barrier(0);
            __builtin_amdgcn_s_setprio(1);
            #pragma unroll
            for (int mi = 0; mi < 4; mi++)
                #pragma unroll
                for (int ni = 0; ni < NI; ni++)
                    acc[4 + mi][ni] = mfma16(af1[mi], bfr[ni], acc[4 + mi][ni]);
            __builtin_amdgcn_s_setprio(0);
            __builtin_amdgcn_s_barrier();
        }
    }

    #pragma unroll
    for (int mi = 0; mi < 8; mi++)
        #pragma unroll
        for (int r = 0; r < 4; r++) {
            long row = m0 + wm + mi * 16 + quad * 4 + r;
            OutT* crow = C + row * (long)N + n0 + wn + l15;
            #pragma unroll
            for (int ni = 0; ni < NI; ni++) {
                float v = acc[mi][ni][r];
                if constexpr (sizeof(OutT) == 2) crow[ni * 16] = f2bf(v);
                else crow[ni * 16] = v;
            }
        }
}

// ---------------- causal flash attention v6: double-buffered K/V, counted vmcnt ----------------
// (round-7 verified: 78.6 us) KB/VB x2, stage t+1 at iter top, counted vmcnt(8) + raw
// s_barrier (loads never drained mid-loop). Ps has no m-dim (PV m=0,1 sequential, V frags
// in regs across both m). 75.3 KB LDS -> 2 blocks/CU.
__global__ __launch_bounds__(256, 2) void attn(const u16* __restrict__ qkv, const u16* __restrict__ vT,
                                               u16* __restrict__ ctx) {
    __shared__ u16 KB[2][64 * 128];    // K tile dbuf: row t (64) x col d (128), swizzled
    __shared__ u16 VB[2][128 * 64];    // V tile dbuf: row d (128) x col t (64), swizzled
    __shared__ u16 Ps[4][16][72];      // [wave][qrow16][t+pad]  (one m at a time)
    __shared__ float Al[4][2][16];     // alpha axis-swap
    const int tid = threadIdx.x;
    const int lane = tid & 63, wave = tid >> 6;
    const int l15 = lane & 15, quad = lane >> 4;
    const int bg = blockIdx.x & 7, b = bg >> 2, g = bg & 3;
    const int rest = blockIdx.x >> 3;
    const int h = g * 4 + (rest & 3);
    const int idx = rest >> 2;
    const int qt = (idx < 8) ? (15 - idx) : (idx - 8);   // complementary pairing
    const int wr = qt * 128 + wave * 32;

    union { bf16x8 v; u16 s[8]; } uo;
    for (int j = 0; j < 8; j++) uo.s[j] = 0x3F80;
    const bf16x8 ones = uo.v;

    bf16x8 qa[2][4];
    for (int m = 0; m < 2; m++) {
        const u16* qp = qkv + (long)(b * SLEN + wr + m * 16 + l15) * 3072 + h * 128 + quad * 8;
        for (int kc = 0; kc < 4; kc++) qa[m][kc] = *(const bf16x8*)(qp + kc * 32);
    }
    float m_i[2] = {-__builtin_inff(), -__builtin_inff()};
    f32x4 l_acc[2];
    f32x4 o[2][8];
    for (int m = 0; m < 2; m++) l_acc[m] = {0.f, 0.f, 0.f, 0.f};
    for (int m = 0; m < 2; m++)
        for (int nf = 0; nf < 8; nf++) o[m][nf] = {0.f, 0.f, 0.f, 0.f};

    const u16* kqb = qkv + (long)b * SLEN * 3072 + 2048 + g * 128;
    const u16* vgb = vT + (long)g * 128 * 4096 + (long)b * SLEN;
    const int xk = (l15 & 7) << 4;
    const int nt = 2 * qt + 2;

    auto stage = [&](int t0, int buf) {
        #pragma unroll
        for (int i = 0; i < 4; ++i) {
            const int j = wave * 4 + i;
            {
                const int row = j * 4 + (lane >> 4);
                const int cs = lane & 15;
                cp16(kqb + (long)(t0 + row) * 3072 + ((cs ^ (row & 7)) * 8), &KB[buf][j * 512]);
            }
            {
                const int row = j * 8 + (lane >> 3);
                const int cs = lane & 7;
                cp16(vgb + (long)row * 4096 + t0 + ((cs ^ (row & 7)) * 8), &VB[buf][j * 512]);
            }
        }
    };

    stage(0, 0);   // tile 0 in flight (8 loads/thread)

    for (int t = 0; t < nt; ++t) {
        const int cur = t & 1;
        const int t0 = t * 64;
        if (t + 1 < nt) {
            stage((t + 1) * 64, cur ^ 1);                       // issue early
            asm volatile("s_waitcnt vmcnt(8)" ::: "memory");    // tile t landed; t+1 in flight
        } else {
            asm volatile("s_waitcnt vmcnt(0)" ::: "memory");
        }
        __builtin_amdgcn_s_barrier();    // all waves' tile-t staging visible

        if (t0 <= wr + 31) {
            bf16x8 kf[4][4];
            #pragma unroll
            for (int nf = 0; nf < 4; nf++)
                #pragma unroll
                for (int kc = 0; kc < 4; kc++)
                    kf[nf][kc] = *(const bf16x8*)((const char*)&KB[cur][0] +
                                  (nf * 16 + l15) * 256 + ((quad * 16 + kc * 64) ^ xk));

            f32x4 sc[2][4];
            for (int m = 0; m < 2; m++)
                for (int nf = 0; nf < 4; nf++) sc[m][nf] = {0.f, 0.f, 0.f, 0.f};
            #pragma unroll
            for (int kc = 0; kc < 4; kc++)
                #pragma unroll
                for (int nf = 0; nf < 4; nf++) {
                    sc[0][nf] = mfma16(kf[nf][kc], qa[0][kc], sc[0][nf]);
                    sc[1][nf] = mfma16(kf[nf][kc], qa[1][kc], sc[1][nf]);
                }
            if (t0 + 63 > wr) {
                #pragma unroll
                for (int m = 0; m < 2; m++) {
                    int qrow = wr + m * 16 + l15;
                    #pragma unroll
                    for (int nf = 0; nf < 4; nf++)
                        #pragma unroll
                        for (int r = 0; r < 4; r++)
                            if (t0 + nf * 16 + quad * 4 + r > qrow) sc[m][nf][r] = -__builtin_inff();
                }
            }
            float alpha[2];
            #pragma unroll
            for (int m = 0; m < 2; m++) {
                float mx = sc[m][0][0];
                #pragma unroll
                for (int nf = 0; nf < 4; nf++)
                    #pragma unroll
                    for (int r = 0; r < 4; r++) mx = fmaxf(mx, sc[m][nf][r]);
                mx = fmaxf(mx, __shfl_xor(mx, 16));
                mx = fmaxf(mx, __shfl_xor(mx, 32));
                float mn = fmaxf(m_i[m], mx);
                alpha[m] = __expf(m_i[m] - mn);
                m_i[m] = mn;
                Al[wave][m][l15] = alpha[m];
            }
            memfence_compiler();
            f32x4 al[2];
            al[0] = *(const f32x4*)&Al[wave][0][quad * 4];
            al[1] = *(const f32x4*)&Al[wave][1][quad * 4];

            // V fragments (both halves) from VB[cur], held in regs across both m
            bf16x8 vfA[8], vfB[8];
            #pragma unroll
            for (int nf = 0; nf < 8; nf++) {
                vfA[nf] = *(const bf16x8*)((const char*)&VB[cur][0] +
                          (nf * 16 + l15) * 128 + ((quad * 16) ^ xk));
                vfB[nf] = *(const bf16x8*)((const char*)&VB[cur][0] +
                          (nf * 16 + l15) * 128 + ((64 + quad * 16) ^ xk));
            }

            // PV: m = 0,1 sequential (Ps reused; per-wave region, in-order DS pipe)
            #pragma unroll
            for (int m = 0; m < 2; m++) {
                #pragma unroll
                for (int nf = 0; nf < 4; nf++) {
                    ushort4 pk;
                    pk.x = f2bf(__expf(sc[m][nf][0] - m_i[m]));
                    pk.y = f2bf(__expf(sc[m][nf][1] - m_i[m]));
                    pk.z = f2bf(__expf(sc[m][nf][2] - m_i[m]));
                    pk.w = f2bf(__expf(sc[m][nf][3] - m_i[m]));
                    *(ushort4*)&Ps[wave][l15][nf * 16 + quad * 4] = pk;
                }
                memfence_compiler();
                #pragma unroll
                for (int nf = 0; nf < 8; nf++)
                    #pragma unroll
                    for (int r = 0; r < 4; r++) o[m][nf][r] *= al[m][r];
                #pragma unroll
                for (int r = 0; r < 4; r++) l_acc[m][r] *= al[m][r];
                bf16x8 pa0 = *(const bf16x8*)&Ps[wave][l15][quad * 8];
                bf16x8 pa1 = *(const bf16x8*)&Ps[wave][l15][32 + quad * 8];
                #pragma unroll
                for (int nf = 0; nf < 8; nf++) {
                    o[m][nf] = mfma16(pa0, vfA[nf], o[m][nf]);
                    o[m][nf] = mfma16(pa1, vfB[nf], o[m][nf]);
                }
                l_acc[m] = mfma16(pa0, ones, l_acc[m]);
                l_acc[m] = mfma16(pa1, ones, l_acc[m]);
                memfence_compiler();   // m=1's P-store must not be hoisted above m=0's reads
            }
        }
        memfence_compiler();
        __builtin_amdgcn_s_barrier();   // buf[cur] readers retired -> stage t+2 may overwrite
    }

    #pragma unroll
    for (int m = 0; m < 2; m++)
        #pragma unroll
        for (int r = 0; r < 4; r++) {
            float inv = 1.f / l_acc[m][r];
            int srow = wr + m * 16 + quad * 4 + r;
            u16* cp = ctx + (long)(b * SLEN + srow) * 2048 + h * 128 + l15;
            #pragma unroll
            for (int nf = 0; nf < 8; nf++) cp[nf * 16] = f2bf(o[m][nf][r] * inv);
        }
}

extern "C" void kernel_launch(void* const* d_in, const int* in_sizes, int n_in,
                              void* d_out, int out_size, void* d_ws, size_t ws_size,
                              hipStream_t stream) {
    const float* x    = (const float*)d_in[0];
    const float* cosi = (const float*)d_in[2];
    const float* sini = (const float*)d_in[3];
    const float* Wq   = (const float*)d_in[4];
    const float* Wk   = (const float*)d_in[5];
    const float* Wv   = (const float*)d_in[6];
    const float* Wo   = (const float*)d_in[7];
    const float* qw   = (const float*)d_in[8];
    const float* kw   = (const float*)d_in[9];
    float* out = (float*)d_out;
    char* ws = (char*)d_ws;

    const size_t MB = 1 << 20;
    u16* qkvb  = (u16*)(ws);             // 4096x3072 bf16 = 24 MB  [0,24)
    u16* vTb   = (u16*)(ws + 24 * MB);   // 512x4096        = 4 MB  [24,28)
    u16* xbf   = (u16*)(ws + 28 * MB);   // 4096x2048       = 16 MB [28,44)
    u16* ctx   = (u16*)(ws + 28 * MB);   // reuses xbf region
    u16* wqkvT = (u16*)(ws + 44 * MB);   // 3072x2048       = 12 MB [44,56)
    u16* woT   = (u16*)(ws + 44 * MB);   // reuses wqkvT region
    u16* qwb   = (u16*)(ws + 56 * MB);
    u16* kwb   = (u16*)(ws + 56 * MB + 256);

    // 1) prep: convert x (8/thread), convert qw/kw, transpose Wq/Wk/Wv into fused wqkvT
    prep_k<<<5633, 256, 0, stream>>>(x, xbf, qw, kw, qwb, kwb, Wq, Wk, Wv, wqkvT);

    // 2) QKV GEMM (8-phase + XCD swizzle): (4096x2048) x (3072x2048)^T -> 4096x3072 bf16
    gemm8p<u16, 4><<<dim3(12, 16), 512, 131072, stream>>>(xbf, wqkvT, qkvb, 3072, 2048);

    // 3) mid: vT transpose, normrope q (vectorized), normrope k, Wo^T
    mid_k<<<22016, 256, 0, stream>>>(qkvb, vTb, qwb, kwb, cosi, sini, Wo, woT);

    // 4) attention (double-buffered, round-7 verified)
    attn<<<dim3(512, 1, 1), 256, 0, stream>>>(qkvb, vTb, ctx);

    // 5) out GEMM (8-phase + XCD swizzle, BN=128 -> 256 blocks, full CU util)
    gemm8p<float, 2><<<dim3(16, 16), 512, 98304, stream>>>(ctx, woT, out, 2048, 2048);
}